// Round 15
// baseline (141.204 us; speedup 1.0000x reference)
//
#include <hip/hip_runtime.h>

// GCN forward: out = PReLU( D^-1/2 (A+I) D^-1/2 (x@W) + b )
//   xsf[i,:] = fp8( dinv[i] * x[i,:] )          (gather payload, 1 B/feat)
//   xai[i,:] = bf16( dinv[i]^2 * x[i,:] )       (EXACT self term)
//   xa[i,:]  = bf16( xai[i,:] + dinv[i] * sum_{s->i} xsf[s,:] )
//   out      = PReLU( xa @ W + b )
// R15 = R14 with the self term taken out of fp8 (it carries weight dinv^2<=1
// and dominated R14's 0.1289 absmax tail; deg-0 nodes are now exact-to-bf16).
// fp8 neighbors keep the k5 win: 128 B gather rows = 1 L3 line per edge,
// one wave gather instruction serves TWO edges. k6 unchanged (R13).

typedef __attribute__((ext_vector_type(8))) short bf16x8_t;
typedef __attribute__((ext_vector_type(4))) float f32x4;
typedef __attribute__((ext_vector_type(2))) float f32x2;

#define N_NODES 100000
#define N_EDGES 500000
#define K_IN    128
#define H_OUT   512
#define MAXDEG  32
#define NEB     1954     // ceil(N_EDGES/256)
#define NMT     782      // ceil(N_NODES/128)

static __device__ __forceinline__ unsigned short f2b(float f) {
    unsigned u = __float_as_uint(f);
    u = (u + 0x7FFFu + ((u >> 16) & 1u)) >> 16;   // RNE
    return (unsigned short)u;
}
static __device__ __forceinline__ float b2lo(unsigned v) {
    return __uint_as_float(v << 16);
}
static __device__ __forceinline__ float b2hi(unsigned v) {
    return __uint_as_float(v & 0xFFFF0000u);
}

// K1: deg histogram + INLINE padded-CSR fill (atomic old value = slot) | prepW
__global__ __launch_bounds__(256) void k1(const int* __restrict__ ei,
                                          int* __restrict__ deg,
                                          int* __restrict__ csrp,
                                          const float* __restrict__ W,
                                          unsigned short* __restrict__ Wt) {
    int b = blockIdx.x;
    if (b < NEB) {
        int e = b * 256 + threadIdx.x;
        if (e < N_EDGES) {
            int s = ei[e];
            int d = ei[N_EDGES + e];
            int r = atomicAdd(&deg[d], 1);
            csrp[d * MAXDEG + r] = s;
        }
    } else {
        int i = (b - NEB) * 256 + threadIdx.x;   // i = n*128+k
        int n = i >> 7, k = i & 127;
        Wt[i] = f2b(W[k * H_OUT + n]);
    }
}

// K2: per 4 features: xsf = fp8x4(dinv*x), xai = 2x packed bf16(dinv^2*x).
__global__ __launch_bounds__(256) void k2(const int* __restrict__ deg,
                                          const float* __restrict__ x,
                                          unsigned* __restrict__ xsf,
                                          unsigned* __restrict__ xai) {
    int i = blockIdx.x * 256 + threadIdx.x;      // 0 .. 3.2M-1
    int row = i >> 5, c = i & 31;
    float d = rsqrtf((float)(deg[row] + 1));
    const float4* x4 = (const float4*)x;
    float4 xv = x4[i];
    int lo   = __builtin_amdgcn_cvt_pk_fp8_f32(d * xv.x, d * xv.y, 0, 0);
    int both = __builtin_amdgcn_cvt_pk_fp8_f32(d * xv.z, d * xv.w, lo, 1);
    xsf[i] = (unsigned)both;
    float dd = d * d;
    unsigned p0 = ((unsigned)f2b(dd * xv.y) << 16) | f2b(dd * xv.x);
    unsigned p1 = ((unsigned)f2b(dd * xv.w) << 16) | f2b(dd * xv.z);
    *(uint2*)&xai[(size_t)row * 64 + 2 * c] = make_uint2(p0, p1);
}

// K5: xa[i] = bf16( xai[i] + dinv[i] * sum_{s->i} xsf[s] ), 1 wave/node.
// l32 = lane&31 covers features 4*l32..+3; half-wave hw = lane>>5 handles
// even/odd edges (one gather dword instruction = 2 edges' 128 B rows).
__global__ __launch_bounds__(256) void k5(const unsigned* __restrict__ xsf,
                                          const unsigned* __restrict__ xai,
                                          const int* __restrict__ csrp,
                                          const int* __restrict__ deg,
                                          unsigned* __restrict__ xa) {
    int wave = threadIdx.x >> 6, lane = threadIdx.x & 63;
    int node = blockIdx.x * 4 + wave;
    if (node >= N_NODES) return;
    int l32 = lane & 31, hw = lane >> 5;

    float a0 = 0.f, a1 = 0.f, a2 = 0.f, a3 = 0.f;
    int cnt = __builtin_amdgcn_readfirstlane(deg[node]);
    const int4* cp = (const int4*)(csrp + node * MAXDEG);

    for (int j = 0; j < cnt; j += 8) {
        int4 ca = cp[(j >> 2)];
        int4 cb = cp[(j >> 2) + 1];
        unsigned idx[8] = {(unsigned)ca.x, (unsigned)ca.y, (unsigned)ca.z, (unsigned)ca.w,
                           (unsigned)cb.x, (unsigned)cb.y, (unsigned)cb.z, (unsigned)cb.w};
        unsigned v[4];
        #pragma unroll
        for (int t = 0; t < 4; ++t) {
            unsigned id = hw ? idx[2 * t + 1] : idx[2 * t];
            id = id < N_NODES ? id : 0u;             // clamp poison pad
            v[t] = xsf[(size_t)id * 32 + l32];
        }
        #pragma unroll
        for (int t = 0; t < 4; ++t) {
            int e = j + 2 * t + hw;                  // this lane's edge number
            unsigned val = (e < cnt) ? v[t] : 0u;
            f32x2 p01 = __builtin_amdgcn_cvt_pk_f32_fp8((int)val, 0);
            f32x2 p23 = __builtin_amdgcn_cvt_pk_f32_fp8((int)val, 1);
            a0 += p01.x; a1 += p01.y; a2 += p23.x; a3 += p23.y;
        }
    }
    // fold the two half-waves (each lane pairs with lane^32)
    a0 += __shfl_xor(a0, 32, 64);
    a1 += __shfl_xor(a1, 32, 64);
    a2 += __shfl_xor(a2, 32, 64);
    a3 += __shfl_xor(a3, 32, 64);

    if (hw == 0) {
        float di = rsqrtf((float)(cnt + 1));
        uint2 self = *(const uint2*)&xai[(size_t)node * 64 + 2 * l32];
        float f0 = b2lo(self.x) + di * a0;
        float f1 = b2hi(self.x) + di * a1;
        float f2 = b2lo(self.y) + di * a2;
        float f3 = b2hi(self.y) + di * a3;
        unsigned d0 = ((unsigned)f2b(f1) << 16) | f2b(f0);
        unsigned d1 = ((unsigned)f2b(f3) << 16) | f2b(f2);
        *(uint2*)&xa[(size_t)node * 64 + 2 * l32] = make_uint2(d0, d1);
    }
}

// K6 (R13): A-resident GEMM. One block per 128-row m-tile (8 waves):
// stage swizzled xa tile once into sA; loop 4 n-chunks staging 128x128 Wt
// into sB; 2m x 4n wave grid, 4x2 frags; epilogue per chunk through ep
// (aliases sB), nontemporal f32x4 stores. Bijective XCD swizzle (q=97,r=6).
__global__ __launch_bounds__(512) void k6(const unsigned short* __restrict__ xa,
                                          const unsigned short* __restrict__ Wt,
                                          const float* __restrict__ bias,
                                          const float* __restrict__ pw,
                                          float* __restrict__ out) {
    __shared__ char smem[65536];
    uint4* sA = (uint4*)smem;              // 32 KB: A tile, persists
    uint4* sB = (uint4*)(smem + 32768);    // 32 KB: Wt chunk
    float* ep = (float*)(smem + 32768);    // epilogue alias over sB

    int orig = blockIdx.x;
    int xcd = orig & 7, loc = orig >> 3;
    int wgid = (xcd < 6 ? xcd * 98 : 588 + (xcd - 6) * 97) + loc;
    const int m0 = wgid * 128;
    const int tid = threadIdx.x;
    const int wave = tid >> 6, lane = tid & 63;

    const uint4* A4 = (const uint4*)xa;
    const uint4* B4 = (const uint4*)Wt;

    // stage A once
    #pragma unroll
    for (int r = 0; r < 4; ++r) {
        int i = tid + r * 512;
        int row = i >> 4, c = i & 15;
        int grow = m0 + row;
        uint4 o = (grow < N_NODES) ? A4[(size_t)grow * 16 + c]
                                   : make_uint4(0u, 0u, 0u, 0u);
        sA[row * 16 + (c ^ (row & 7))] = o;
    }

    const int wr = wave >> 2, wc = wave & 3;     // 2m x 4n wave grid
    const int l16 = lane & 15, lq = lane >> 4;

    for (int nc = 0; nc < 4; ++nc) {
        #pragma unroll
        for (int r = 0; r < 4; ++r) {
            int i = tid + r * 512;
            int row = i >> 4, c = i & 15;
            sB[row * 16 + (c ^ (row & 7))] = B4[(size_t)(nc * 128 + row) * 16 + c];
        }
        __syncthreads();

        f32x4 acc[4][2];
        #pragma unroll
        for (int m = 0; m < 4; ++m)
            #pragma unroll
            for (int n = 0; n < 2; ++n)
                acc[m][n] = (f32x4){0.f, 0.f, 0.f, 0.f};

        #pragma unroll
        for (int kk = 0; kk < 4; ++kk) {
            bf16x8_t av[4], bv[2];
            #pragma unroll
            for (int m = 0; m < 4; ++m) {
                int row = wr * 64 + m * 16 + l16;
                av[m] = __builtin_bit_cast(bf16x8_t, sA[row * 16 + ((kk * 4 + lq) ^ (row & 7))]);
            }
            #pragma unroll
            for (int n = 0; n < 2; ++n) {
                int row = wc * 32 + n * 16 + l16;
                bv[n] = __builtin_bit_cast(bf16x8_t, sB[row * 16 + ((kk * 4 + lq) ^ (row & 7))]);
            }
            #pragma unroll
            for (int m = 0; m < 4; ++m)
                #pragma unroll
                for (int n = 0; n < 2; ++n)
                    acc[m][n] = __builtin_amdgcn_mfma_f32_16x16x32_bf16(av[m], bv[n], acc[m][n], 0, 0, 0);
        }
        __syncthreads();   // sB reads done before ep overwrites it

        float bn[2], pn[2];
        #pragma unroll
        for (int n = 0; n < 2; ++n) {
            int gn = nc * 128 + wc * 32 + n * 16 + l16;
            bn[n] = bias[gn];
            pn[n] = pw[gn];
        }

        #pragma unroll
        for (int h = 0; h < 2; ++h) {
            if (wr == h) {
                #pragma unroll
                for (int m = 0; m < 4; ++m)
                    #pragma unroll
                    for (int r = 0; r < 4; ++r) {
                        int row = m * 16 + lq * 4 + r;
                        #pragma unroll
                        for (int n = 0; n < 2; ++n) {
                            float t = acc[m][n][r] + bn[n];
                            float v = t >= 0.f ? t : pn[n] * t;
                            ep[row * 128 + wc * 32 + n * 16 + l16] = v;
                        }
                    }
            }
            __syncthreads();
            #pragma unroll
            for (int it = 0; it < 4; ++it) {
                int row = it * 16 + (tid >> 5);
                int gm = m0 + h * 64 + row;
                if (gm < N_NODES) {
                    int c4 = tid & 31;
                    f32x4 v = *(const f32x4*)&ep[row * 128 + c4 * 4];
                    __builtin_nontemporal_store(v, (f32x4*)&out[(size_t)gm * H_OUT + nc * 128 + c4 * 4]);
                }
            }
            __syncthreads();
        }
    }
}

extern "C" void kernel_launch(void* const* d_in, const int* in_sizes, int n_in,
                              void* d_out, int out_size, void* d_ws, size_t ws_size,
                              hipStream_t stream) {
    const float* x    = (const float*)d_in[0];
    const int*   ei   = (const int*)d_in[1];
    const float* W    = (const float*)d_in[2];
    const float* bias = (const float*)d_in[3];
    const float* pw   = (const float*)d_in[4];
    float* out = (float*)d_out;

    char* ws = (char*)d_ws;
    size_t off = 0;
    auto alloc = [&](size_t bytes) -> void* {
        void* p = ws + off;
        off += (bytes + 255) & ~(size_t)255;
        return p;
    };
    unsigned*       xsf  = (unsigned*)alloc((size_t)N_NODES * K_IN);           // 12.8 MB fp8
    unsigned*       xai  = (unsigned*)alloc((size_t)N_NODES * K_IN * 2);       // 25.6 MB bf16 self
    unsigned*       xa   = (unsigned*)alloc((size_t)N_NODES * K_IN * 2);       // 25.6 MB bf16
    unsigned short* Wt   = (unsigned short*)alloc((size_t)K_IN * H_OUT * 2);   // 131 KB
    int*            deg  = (int*)alloc((size_t)N_NODES * 4);                   // 400 KB
    int*            csrp = (int*)alloc((size_t)N_NODES * MAXDEG * 4);          // 12.8 MB
    (void)ws_size; (void)in_sizes; (void)n_in; (void)out_size;

    hipMemsetAsync(deg, 0, (size_t)N_NODES * 4, stream);

    k1 <<<NEB + 256, 256, 0, stream>>>(ei, deg, csrp, W, Wt);
    k2 <<<12500, 256, 0, stream>>>(deg, x, xsf, xai);
    k5 <<<(N_NODES + 3) / 4, 256, 0, stream>>>(xsf, xai, csrp, deg, xa);
    k6 <<<NMT, 512, 0, stream>>>((const unsigned short*)xa,
                                 (const unsigned short*)Wt, bias, pw, out);
}

// Round 16
// 127.634 us; speedup vs baseline: 1.1063x; 1.1063x over previous
//
#include <hip/hip_runtime.h>

// GCN forward: out = PReLU( D^-1/2 (A+I) D^-1/2 (x@W) + b )
//   xraw[i,:] = bf16( x[i,:] )                          (no deg dependency!)
//   xa[i,:]   = bf16( di * ( sum_{s->i} ds*xraw[s] + di*xraw[i] ) ), d=rsqrt(deg+1)
//   out       = PReLU( xa @ W + b )
// R16 = R13 base (fp8 of R14/R15 reverted — measured regression) with the
// conversion folded into k1's heterogeneous grid (raw bf16 needs no deg, so
// it overlaps the histogram's atomic blocks); k5 applies per-edge weights
// ds = rsqrt(deg[s]+1) via wave-uniform broadcast loads from L2-resident deg.
// Chain: memset -> k1{hist+fill | prepW | convert} -> k5 -> k6. 4 dispatches.

typedef __attribute__((ext_vector_type(8))) short bf16x8_t;
typedef __attribute__((ext_vector_type(4))) float f32x4;

#define N_NODES 100000
#define N_EDGES 500000
#define K_IN    128
#define H_OUT   512
#define MAXDEG  32
#define NEB     1954     // ceil(N_EDGES/256) histogram blocks
#define NWB     256      // prepW blocks (512*128/256)
#define NCB     12500    // conversion blocks (3.2M float4 / 256)
#define NMT     782      // ceil(N_NODES/128)

static __device__ __forceinline__ unsigned short f2b(float f) {
    unsigned u = __float_as_uint(f);
    u = (u + 0x7FFFu + ((u >> 16) & 1u)) >> 16;   // RNE
    return (unsigned short)u;
}
static __device__ __forceinline__ float b2lo(unsigned v) {
    return __uint_as_float(v << 16);
}
static __device__ __forceinline__ float b2hi(unsigned v) {
    return __uint_as_float(v & 0xFFFF0000u);
}

// K1: heterogeneous — [0,NEB): deg histogram + inline padded-CSR fill
//                     [NEB,NEB+NWB): W transpose -> bf16
//                     [NEB+NWB, +NCB): x -> bf16 raw conversion (streams,
//                                      overlaps the atomic-bound blocks)
__global__ __launch_bounds__(256) void k1(const int* __restrict__ ei,
                                          int* __restrict__ deg,
                                          int* __restrict__ csrp,
                                          const float* __restrict__ W,
                                          unsigned short* __restrict__ Wt,
                                          const float* __restrict__ x,
                                          unsigned* __restrict__ xraw) {
    int b = blockIdx.x;
    if (b < NEB) {
        int e = b * 256 + threadIdx.x;
        if (e < N_EDGES) {
            int s = ei[e];
            int d = ei[N_EDGES + e];
            int r = atomicAdd(&deg[d], 1);
            csrp[d * MAXDEG + r] = s;
        }
    } else if (b < NEB + NWB) {
        int i = (b - NEB) * 256 + threadIdx.x;   // i = n*128+k
        int n = i >> 7, k = i & 127;
        Wt[i] = f2b(W[k * H_OUT + n]);
    } else {
        int t = (b - NEB - NWB) * 256 + threadIdx.x;   // 0 .. 3.2M-1 (exact)
        const float4* x4 = (const float4*)x;
        float4 xv = x4[t];
        unsigned p0 = ((unsigned)f2b(xv.y) << 16) | f2b(xv.x);
        unsigned p1 = ((unsigned)f2b(xv.w) << 16) | f2b(xv.z);
        *(uint2*)&xraw[2 * (size_t)t] = make_uint2(p0, p1);
    }
}

// K5: xa[i] = bf16( di*(sum_s ds*xraw[s] + di*xraw[i]) ), 1 wave/node.
// Adjacency as int4 pairs; gathers unconditional (clamped idx); per-edge
// ds from broadcast deg[s] loads; tail masked via weight w=0 (gathered
// values are always finite bf16, so w=0 is exact).
__global__ __launch_bounds__(256) void k5(const unsigned* __restrict__ xraw,
                                          const int* __restrict__ csrp,
                                          const int* __restrict__ deg,
                                          unsigned* __restrict__ xa) {
    int wave = threadIdx.x >> 6, lane = threadIdx.x & 63;
    int node = blockIdx.x * 4 + wave;
    if (node >= N_NODES) return;

    unsigned sv = xraw[(size_t)node * 64 + lane];
    int cnt = __builtin_amdgcn_readfirstlane(deg[node]);
    float a0 = 0.f, a1 = 0.f;

    const int4* cp = (const int4*)(csrp + node * MAXDEG);
    for (int j = 0; j < cnt; j += 8) {
        int4 ca = cp[(j >> 2)];
        int4 cb = cp[(j >> 2) + 1];
        unsigned idx[8] = {(unsigned)ca.x, (unsigned)ca.y, (unsigned)ca.z, (unsigned)ca.w,
                           (unsigned)cb.x, (unsigned)cb.y, (unsigned)cb.z, (unsigned)cb.w};
        unsigned v[8];
        int dg[8];
        #pragma unroll
        for (int t = 0; t < 8; ++t) {
            unsigned id = idx[t] < N_NODES ? idx[t] : 0u;   // clamp poison pad
            v[t] = xraw[(size_t)id * 64 + lane];            // 256 B row gather
            dg[t] = deg[id];                                // broadcast, L2-hot
        }
        int rem = cnt - j;   // wave-uniform
        #pragma unroll
        for (int t = 0; t < 8; ++t) {
            float w = (t < rem) ? rsqrtf((float)(dg[t] + 1)) : 0.f;
            a0 += w * b2lo(v[t]);
            a1 += w * b2hi(v[t]);
        }
    }
    float di = rsqrtf((float)(cnt + 1));
    float f0 = di * (a0 + di * b2lo(sv));
    float f1 = di * (a1 + di * b2hi(sv));
    xa[(size_t)node * 64 + lane] = ((unsigned)f2b(f1) << 16) | f2b(f0);
}

// K6 (R13, unchanged): A-resident GEMM. One block per 128-row m-tile
// (8 waves): stage swizzled xa tile once into sA; loop 4 n-chunks staging
// 128x128 Wt into sB; 2m x 4n wave grid, 4x2 frags; epilogue per chunk
// through ep (aliases sB), nontemporal f32x4 stores. Bijective XCD swizzle
// for NWG=782 (q=97, r=6).
__global__ __launch_bounds__(512) void k6(const unsigned short* __restrict__ xa,
                                          const unsigned short* __restrict__ Wt,
                                          const float* __restrict__ bias,
                                          const float* __restrict__ pw,
                                          float* __restrict__ out) {
    __shared__ char smem[65536];
    uint4* sA = (uint4*)smem;              // 32 KB: A tile, persists
    uint4* sB = (uint4*)(smem + 32768);    // 32 KB: Wt chunk
    float* ep = (float*)(smem + 32768);    // epilogue alias over sB

    int orig = blockIdx.x;
    int xcd = orig & 7, loc = orig >> 3;
    int wgid = (xcd < 6 ? xcd * 98 : 588 + (xcd - 6) * 97) + loc;
    const int m0 = wgid * 128;
    const int tid = threadIdx.x;
    const int wave = tid >> 6, lane = tid & 63;

    const uint4* A4 = (const uint4*)xa;
    const uint4* B4 = (const uint4*)Wt;

    // stage A once
    #pragma unroll
    for (int r = 0; r < 4; ++r) {
        int i = tid + r * 512;
        int row = i >> 4, c = i & 15;
        int grow = m0 + row;
        uint4 o = (grow < N_NODES) ? A4[(size_t)grow * 16 + c]
                                   : make_uint4(0u, 0u, 0u, 0u);
        sA[row * 16 + (c ^ (row & 7))] = o;
    }

    const int wr = wave >> 2, wc = wave & 3;     // 2m x 4n wave grid
    const int l16 = lane & 15, lq = lane >> 4;

    for (int nc = 0; nc < 4; ++nc) {
        #pragma unroll
        for (int r = 0; r < 4; ++r) {
            int i = tid + r * 512;
            int row = i >> 4, c = i & 15;
            sB[row * 16 + (c ^ (row & 7))] = B4[(size_t)(nc * 128 + row) * 16 + c];
        }
        __syncthreads();

        f32x4 acc[4][2];
        #pragma unroll
        for (int m = 0; m < 4; ++m)
            #pragma unroll
            for (int n = 0; n < 2; ++n)
                acc[m][n] = (f32x4){0.f, 0.f, 0.f, 0.f};

        #pragma unroll
        for (int kk = 0; kk < 4; ++kk) {
            bf16x8_t av[4], bv[2];
            #pragma unroll
            for (int m = 0; m < 4; ++m) {
                int row = wr * 64 + m * 16 + l16;
                av[m] = __builtin_bit_cast(bf16x8_t, sA[row * 16 + ((kk * 4 + lq) ^ (row & 7))]);
            }
            #pragma unroll
            for (int n = 0; n < 2; ++n) {
                int row = wc * 32 + n * 16 + l16;
                bv[n] = __builtin_bit_cast(bf16x8_t, sB[row * 16 + ((kk * 4 + lq) ^ (row & 7))]);
            }
            #pragma unroll
            for (int m = 0; m < 4; ++m)
                #pragma unroll
                for (int n = 0; n < 2; ++n)
                    acc[m][n] = __builtin_amdgcn_mfma_f32_16x16x32_bf16(av[m], bv[n], acc[m][n], 0, 0, 0);
        }
        __syncthreads();   // sB reads done before ep overwrites it

        float bn[2], pn[2];
        #pragma unroll
        for (int n = 0; n < 2; ++n) {
            int gn = nc * 128 + wc * 32 + n * 16 + l16;
            bn[n] = bias[gn];
            pn[n] = pw[gn];
        }

        #pragma unroll
        for (int h = 0; h < 2; ++h) {
            if (wr == h) {
                #pragma unroll
                for (int m = 0; m < 4; ++m)
                    #pragma unroll
                    for (int r = 0; r < 4; ++r) {
                        int row = m * 16 + lq * 4 + r;
                        #pragma unroll
                        for (int n = 0; n < 2; ++n) {
                            float t = acc[m][n][r] + bn[n];
                            float v = t >= 0.f ? t : pn[n] * t;
                            ep[row * 128 + wc * 32 + n * 16 + l16] = v;
                        }
                    }
            }
            __syncthreads();
            #pragma unroll
            for (int it = 0; it < 4; ++it) {
                int row = it * 16 + (tid >> 5);
                int gm = m0 + h * 64 + row;
                if (gm < N_NODES) {
                    int c4 = tid & 31;
                    f32x4 v = *(const f32x4*)&ep[row * 128 + c4 * 4];
                    __builtin_nontemporal_store(v, (f32x4*)&out[(size_t)gm * H_OUT + nc * 128 + c4 * 4]);
                }
            }
            __syncthreads();
        }
    }
}

extern "C" void kernel_launch(void* const* d_in, const int* in_sizes, int n_in,
                              void* d_out, int out_size, void* d_ws, size_t ws_size,
                              hipStream_t stream) {
    const float* x    = (const float*)d_in[0];
    const int*   ei   = (const int*)d_in[1];
    const float* W    = (const float*)d_in[2];
    const float* bias = (const float*)d_in[3];
    const float* pw   = (const float*)d_in[4];
    float* out = (float*)d_out;

    char* ws = (char*)d_ws;
    size_t off = 0;
    auto alloc = [&](size_t bytes) -> void* {
        void* p = ws + off;
        off += (bytes + 255) & ~(size_t)255;
        return p;
    };
    unsigned*       xraw = (unsigned*)alloc((size_t)N_NODES * K_IN * 2);       // 25.6 MB bf16
    unsigned*       xa   = (unsigned*)alloc((size_t)N_NODES * K_IN * 2);       // 25.6 MB bf16
    unsigned short* Wt   = (unsigned short*)alloc((size_t)K_IN * H_OUT * 2);   // 131 KB
    int*            deg  = (int*)alloc((size_t)N_NODES * 4);                   // 400 KB
    int*            csrp = (int*)alloc((size_t)N_NODES * MAXDEG * 4);          // 12.8 MB
    (void)ws_size; (void)in_sizes; (void)n_in; (void)out_size;

    hipMemsetAsync(deg, 0, (size_t)N_NODES * 4, stream);

    k1 <<<NEB + NWB + NCB, 256, 0, stream>>>(ei, deg, csrp, W, Wt, x, xraw);
    k5 <<<(N_NODES + 3) / 4, 256, 0, stream>>>(xraw, csrp, deg, xa);
    k6 <<<NMT, 512, 0, stream>>>((const unsigned short*)xa,
                                 (const unsigned short*)Wt, bias, pw, out);
}